// Round 2
// baseline (159.538 us; speedup 1.0000x reference)
//
#include <hip/hip_runtime.h>
#include <math.h>

// SPLFullLoss: x, ref f32[B=32, N=4096, D=512] -> scalar
//   a = -(1/(N*B)) * sum_rows Sxr/(max(sqrt(Sxx),eps)*max(sqrt(Srr),eps))  (rows along D)
//   b = -(1/(D*B)) * sum_cols Sxr/(max(sqrt(Sxx),eps)*max(sqrt(Srr),eps))  (cols along N)
// Single streaming pass; row reductions batched OUT of the load loop so the
// wave streams loads without per-row cross-lane dependency chains.

#define BB 32
#define NN 4096
#define DD 512

static constexpr float EPS = 1e-12f;
static constexpr int ROWS_PER_BLOCK = 32;
static constexpr int BPB   = NN / ROWS_PER_BLOCK;    // 128 blocks per batch
static constexpr int NWAVE = 4;                      // 256 threads
static constexpr int RPW   = ROWS_PER_BLOCK / NWAVE; // 8 rows per wave
static constexpr int SUB   = 4;                      // rows per sub-batch
static constexpr int NSUB  = RPW / SUB;              // 2

// ws layout (floats): cxx[B*D] | crr[B*D] | cxr[B*D] | row_tot[1]
static constexpr size_t WS_CXX = 0;
static constexpr size_t WS_CRR = (size_t)BB * DD;
static constexpr size_t WS_CXR = (size_t)2 * BB * DD;
static constexpr size_t WS_ROW = (size_t)3 * BB * DD;
static constexpr size_t WS_FLOATS = WS_ROW + 1;

__global__ __launch_bounds__(256) void spl_pass1(
    const float* __restrict__ x, const float* __restrict__ r, float* __restrict__ ws) {
  // flat LDS, 3072 floats = 12 KiB; two uses (never simultaneously):
  //   rowbuf:  [wave][m][row4][64 lanes]      -> ((wave*3+m)*SUB+rr)*64 + lane
  //   colbuf:  [wave][m][256 d]               -> (wave*3+m)*256 + d
  __shared__ float smem[NWAVE * 3 * SUB * 64];
  __shared__ float ldsrow[NWAVE];

  const int tid  = threadIdx.x;
  const int wave = tid >> 6;
  const int lane = tid & 63;
  const int blk  = blockIdx.x;
  const int b    = blk / BPB;
  const int bib  = blk % BPB;
  const int n0   = bib * ROWS_PER_BLOCK + wave * RPW;

  float cxx[8], crr[8], cxr[8];
#pragma unroll
  for (int j = 0; j < 8; ++j) { cxx[j] = 0.f; crr[j] = 0.f; cxr[j] = 0.f; }
  float rowacc = 0.f;  // accumulated 16x redundantly; scaled by 1/16 at the end

  const size_t base_b = (size_t)b * NN * DD;
  const int rgrp = lane >> 4;  // which of the 4 rows this lane reduces
  const int rj   = lane & 15;

  for (int s = 0; s < NSUB; ++s) {
    // ---- streaming phase: loads + FMA + 3 ds_writes per row, no cross-lane ops
#pragma unroll
    for (int rr = 0; rr < SUB; ++rr) {
      const int n = n0 + s * SUB + rr;
      const float4* xp = (const float4*)(x + base_b + (size_t)n * DD);
      const float4* rp = (const float4*)(r + base_b + (size_t)n * DD);
      const float4 x0 = xp[lane];
      const float4 x1 = xp[lane + 64];
      const float4 r0 = rp[lane];
      const float4 r1 = rp[lane + 64];

      float sxx = 0.f, srr = 0.f, sxr = 0.f;
      {
        const float xs[4] = {x0.x, x0.y, x0.z, x0.w};
        const float rs[4] = {r0.x, r0.y, r0.z, r0.w};
#pragma unroll
        for (int j = 0; j < 4; ++j) {
          const float pxx = xs[j] * xs[j];
          const float prr = rs[j] * rs[j];
          const float pxr = xs[j] * rs[j];
          sxx += pxx; srr += prr; sxr += pxr;
          cxx[j] += pxx; crr[j] += prr; cxr[j] += pxr;
        }
      }
      {
        const float xs[4] = {x1.x, x1.y, x1.z, x1.w};
        const float rs[4] = {r1.x, r1.y, r1.z, r1.w};
#pragma unroll
        for (int j = 0; j < 4; ++j) {
          const float pxx = xs[j] * xs[j];
          const float prr = rs[j] * rs[j];
          const float pxr = xs[j] * rs[j];
          sxx += pxx; srr += prr; sxr += pxr;
          cxx[4 + j] += pxx; crr[4 + j] += prr; cxr[4 + j] += pxr;
        }
      }
      smem[((wave * 3 + 0) * SUB + rr) * 64 + lane] = sxx;
      smem[((wave * 3 + 1) * SUB + rr) * 64 + lane] = srr;
      smem[((wave * 3 + 2) * SUB + rr) * 64 + lane] = sxr;
    }

    // ---- batched row reduction (wave-local; 4 rows in parallel, 16 lanes each)
    float vs[3];
#pragma unroll
    for (int m = 0; m < 3; ++m) {
      const float* p = &smem[((wave * 3 + m) * SUB + rgrp) * 64];
      float v = p[rj] + p[rj + 16] + p[rj + 32] + p[rj + 48];
#pragma unroll
      for (int off = 1; off < 16; off <<= 1) v += __shfl_xor(v, off, 64);
      vs[m] = v;
    }
    const float nx = fmaxf(sqrtf(vs[0]), EPS);
    const float nr = fmaxf(sqrtf(vs[1]), EPS);
    rowacc += vs[2] / (nx * nr);  // every lane in the 16-group adds (16x total)
  }

  // wave-reduce rowacc (sum over all 64 lanes = 16x the true sum)
#pragma unroll
  for (int off = 1; off < 64; off <<= 1) rowacc += __shfl_xor(rowacc, off, 64);
  if (lane == 0) ldsrow[wave] = rowacc;

  // ---- column exchange, half 0 (d in [0,256)), reusing smem as colbuf
  __syncthreads();
  {
    float4* cb = (float4*)smem;
#pragma unroll
    for (int m = 0; m < 3; ++m) {
      const float* c = (m == 0) ? cxx : (m == 1) ? crr : cxr;
      cb[(wave * 3 + m) * 64 + lane] = make_float4(c[0], c[1], c[2], c[3]);
    }
  }
  __syncthreads();
  for (int i = tid; i < 768; i += 256) {
    const int m = i >> 8;
    const int d = i & 255;
    const float sum = smem[(0 * 3 + m) * 256 + d] + smem[(1 * 3 + m) * 256 + d] +
                      smem[(2 * 3 + m) * 256 + d] + smem[(3 * 3 + m) * 256 + d];
    atomicAdd(ws + (size_t)m * BB * DD + (size_t)b * DD + d, sum);
  }

  // ---- column exchange, half 1 (d in [256,512))
  __syncthreads();
  {
    float4* cb = (float4*)smem;
#pragma unroll
    for (int m = 0; m < 3; ++m) {
      const float* c = (m == 0) ? cxx : (m == 1) ? crr : cxr;
      cb[(wave * 3 + m) * 64 + lane] = make_float4(c[4], c[5], c[6], c[7]);
    }
  }
  __syncthreads();
  for (int i = tid; i < 768; i += 256) {
    const int m = i >> 8;
    const int d = i & 255;
    const float sum = smem[(0 * 3 + m) * 256 + d] + smem[(1 * 3 + m) * 256 + d] +
                      smem[(2 * 3 + m) * 256 + d] + smem[(3 * 3 + m) * 256 + d];
    atomicAdd(ws + (size_t)m * BB * DD + (size_t)b * DD + 256 + d, sum);
  }

  if (tid == 0) {
    const float tot = (ldsrow[0] + ldsrow[1] + ldsrow[2] + ldsrow[3]) * 0.0625f;
    atomicAdd(ws + WS_ROW, tot);
  }
}

__global__ __launch_bounds__(256) void spl_pass2(const float* __restrict__ ws,
                                                 float* __restrict__ out) {
  const int tid = threadIdx.x;
  const float* cxx_g = ws + WS_CXX;
  const float* crr_g = ws + WS_CRR;
  const float* cxr_g = ws + WS_CXR;

  float acc = 0.f;
  for (int i = tid; i < BB * DD; i += 256) {
    const float sxx = cxx_g[i];
    const float srr = crr_g[i];
    const float sxr = cxr_g[i];
    const float nx = fmaxf(sqrtf(sxx), EPS);
    const float nr = fmaxf(sqrtf(srr), EPS);
    acc += sxr / (nx * nr);
  }
#pragma unroll
  for (int off = 1; off < 64; off <<= 1) acc += __shfl_xor(acc, off, 64);

  __shared__ float wsum[4];
  if ((tid & 63) == 0) wsum[tid >> 6] = acc;
  __syncthreads();
  if (tid == 0) {
    const float colsum = wsum[0] + wsum[1] + wsum[2] + wsum[3];
    const float rowsum = ws[WS_ROW];
    const float a = -rowsum / ((float)NN * (float)BB);
    const float b = -colsum / ((float)DD * (float)BB);
    out[0] = a + b;
  }
}

extern "C" void kernel_launch(void* const* d_in, const int* in_sizes, int n_in,
                              void* d_out, int out_size, void* d_ws, size_t ws_size,
                              hipStream_t stream) {
  const float* x = (const float*)d_in[0];
  const float* r = (const float*)d_in[1];
  float* out = (float*)d_out;
  float* ws = (float*)d_ws;

  (void)in_sizes; (void)n_in; (void)out_size; (void)ws_size;

  hipMemsetAsync(ws, 0, WS_FLOATS * sizeof(float), stream);
  spl_pass1<<<BB * BPB, 256, 0, stream>>>(x, r, ws);
  spl_pass2<<<1, 256, 0, stream>>>(ws, out);
}

// Round 3
// 152.241 us; speedup vs baseline: 1.0479x; 1.0479x over previous
//
#include <hip/hip_runtime.h>
#include <math.h>

// SPLFullLoss: x, ref f32[B=32, N=4096, D=512] -> scalar
//   a = -(1/(N*B)) * sum_rows Sxr/(max(sqrt(Sxx),eps)*max(sqrt(Srr),eps))  (rows along D)
//   b = -(1/(D*B)) * sum_cols Sxr/(max(sqrt(Sxx),eps)*max(sqrt(Srr),eps))  (cols along N)
// R1 structure (proven 40-VGPR, conflict-free) + two-phase column exchange so
// LDS = 12.4 KiB -> 8 blocks/CU co-resident (one uniform dispatch round).

#define BB 32
#define NN 4096
#define DD 512

static constexpr float EPS = 1e-12f;
static constexpr int BPB   = 64;        // blocks per batch
static constexpr int RPB   = NN / BPB;  // 64 rows per block
static constexpr int NWAVE = 4;         // 256 threads
static constexpr int RPW   = RPB / NWAVE; // 16 rows per wave

// ws layout (floats): cxx[B*D] | crr[B*D] | cxr[B*D] | row_tot[1]
static constexpr size_t WS_CXX = 0;
static constexpr size_t WS_CRR = (size_t)BB * DD;
static constexpr size_t WS_CXR = (size_t)2 * BB * DD;
static constexpr size_t WS_ROW = (size_t)3 * BB * DD;
static constexpr size_t WS_FLOATS = WS_ROW + 1;

__global__ __launch_bounds__(256, 8) void spl_pass1(
    const float* __restrict__ x, const float* __restrict__ r, float* __restrict__ ws) {
  // col exchange buffer, half-D at a time: [wave][m][256] floats = 12 KiB
  __shared__ float lds[NWAVE][3][DD / 2];
  __shared__ float ldsrow[NWAVE];

  const int tid  = threadIdx.x;
  const int wave = tid >> 6;
  const int lane = tid & 63;
  const int blk  = blockIdx.x;
  const int b    = blk / BPB;
  const int bib  = blk % BPB;
  const int n0   = bib * RPB + wave * RPW;

  float cxx[8], crr[8], cxr[8];
#pragma unroll
  for (int j = 0; j < 8; ++j) { cxx[j] = 0.f; crr[j] = 0.f; cxr[j] = 0.f; }
  float rowacc = 0.f;

  const size_t base_b = (size_t)b * NN * DD;

  for (int rr = 0; rr < RPW; ++rr) {
    const int n = n0 + rr;
    const float4* xp = (const float4*)(x + base_b + (size_t)n * DD);
    const float4* rp = (const float4*)(r + base_b + (size_t)n * DD);
    float4 x0 = xp[lane];
    float4 x1 = xp[lane + 64];
    float4 r0 = rp[lane];
    float4 r1 = rp[lane + 64];

    float sxx = 0.f, srr = 0.f, sxr = 0.f;
    {
      const float xs[4] = {x0.x, x0.y, x0.z, x0.w};
      const float rs[4] = {r0.x, r0.y, r0.z, r0.w};
#pragma unroll
      for (int j = 0; j < 4; ++j) {
        const float pxx = xs[j] * xs[j];
        const float prr = rs[j] * rs[j];
        const float pxr = xs[j] * rs[j];
        sxx += pxx; srr += prr; sxr += pxr;
        cxx[j] += pxx; crr[j] += prr; cxr[j] += pxr;
      }
    }
    {
      const float xs[4] = {x1.x, x1.y, x1.z, x1.w};
      const float rs[4] = {r1.x, r1.y, r1.z, r1.w};
#pragma unroll
      for (int j = 0; j < 4; ++j) {
        const float pxx = xs[j] * xs[j];
        const float prr = rs[j] * rs[j];
        const float pxr = xs[j] * rs[j];
        sxx += pxx; srr += prr; sxr += pxr;
        cxx[4 + j] += pxx; crr[4 + j] += prr; cxr[4 + j] += pxr;
      }
    }
    // wave64 butterfly: every lane ends with the full row sums
#pragma unroll
    for (int off = 1; off < 64; off <<= 1) {
      sxx += __shfl_xor(sxx, off, 64);
      srr += __shfl_xor(srr, off, 64);
      sxr += __shfl_xor(sxr, off, 64);
    }
    const float nx = fmaxf(sqrtf(sxx), EPS);
    const float nr = fmaxf(sqrtf(srr), EPS);
    rowacc += sxr / (nx * nr);
  }

  if (lane == 0) ldsrow[wave] = rowacc;

  // ---- column exchange, half 0: d in [0,256), reg slots 0..3
  __syncthreads();
  {
    float4* cb = (float4*)&lds[0][0][0];  // [wave*3+m][64] float4s
#pragma unroll
    for (int m = 0; m < 3; ++m) {
      const float* c = (m == 0) ? cxx : (m == 1) ? crr : cxr;
      cb[(wave * 3 + m) * 64 + lane] = make_float4(c[0], c[1], c[2], c[3]);
    }
  }
  __syncthreads();
  for (int i = tid; i < 768; i += 256) {
    const int m = i >> 8;
    const int d = i & 255;
    const float sum = lds[0][m][d] + lds[1][m][d] + lds[2][m][d] + lds[3][m][d];
    atomicAdd(ws + (size_t)m * BB * DD + (size_t)b * DD + d, sum);
  }

  // ---- column exchange, half 1: d in [256,512), reg slots 4..7
  __syncthreads();
  {
    float4* cb = (float4*)&lds[0][0][0];
#pragma unroll
    for (int m = 0; m < 3; ++m) {
      const float* c = (m == 0) ? cxx : (m == 1) ? crr : cxr;
      cb[(wave * 3 + m) * 64 + lane] = make_float4(c[4], c[5], c[6], c[7]);
    }
  }
  __syncthreads();
  for (int i = tid; i < 768; i += 256) {
    const int m = i >> 8;
    const int d = i & 255;
    const float sum = lds[0][m][d] + lds[1][m][d] + lds[2][m][d] + lds[3][m][d];
    atomicAdd(ws + (size_t)m * BB * DD + (size_t)b * DD + 256 + d, sum);
  }

  if (tid == 0) {
    atomicAdd(ws + WS_ROW, ldsrow[0] + ldsrow[1] + ldsrow[2] + ldsrow[3]);
  }
}

__global__ __launch_bounds__(256) void spl_pass2(const float* __restrict__ ws,
                                                 float* __restrict__ out) {
  const int tid = threadIdx.x;
  const float* cxx_g = ws + WS_CXX;
  const float* crr_g = ws + WS_CRR;
  const float* cxr_g = ws + WS_CXR;

  float acc = 0.f;
  for (int i = tid; i < BB * DD; i += 256) {
    const float sxx = cxx_g[i];
    const float srr = crr_g[i];
    const float sxr = cxr_g[i];
    const float nx = fmaxf(sqrtf(sxx), EPS);
    const float nr = fmaxf(sqrtf(srr), EPS);
    acc += sxr / (nx * nr);
  }
#pragma unroll
  for (int off = 1; off < 64; off <<= 1) acc += __shfl_xor(acc, off, 64);

  __shared__ float wsum[4];
  if ((tid & 63) == 0) wsum[tid >> 6] = acc;
  __syncthreads();
  if (tid == 0) {
    const float colsum = wsum[0] + wsum[1] + wsum[2] + wsum[3];
    const float rowsum = ws[WS_ROW];
    const float a = -rowsum / ((float)NN * (float)BB);
    const float b = -colsum / ((float)DD * (float)BB);
    out[0] = a + b;
  }
}

extern "C" void kernel_launch(void* const* d_in, const int* in_sizes, int n_in,
                              void* d_out, int out_size, void* d_ws, size_t ws_size,
                              hipStream_t stream) {
  const float* x = (const float*)d_in[0];
  const float* r = (const float*)d_in[1];
  float* out = (float*)d_out;
  float* ws = (float*)d_ws;

  (void)in_sizes; (void)n_in; (void)out_size; (void)ws_size;

  hipMemsetAsync(ws, 0, WS_FLOATS * sizeof(float), stream);
  spl_pass1<<<BB * BPB, 256, 0, stream>>>(x, r, ws);
  spl_pass2<<<1, 256, 0, stream>>>(ws, out);
}

// Round 4
// 146.815 us; speedup vs baseline: 1.0867x; 1.0370x over previous
//
#include <hip/hip_runtime.h>
#include <math.h>

// SPLFullLoss: x, ref f32[B=32, N=4096, D=512] -> scalar
//   a = -(1/(N*B)) * sum_rows Sxr/(max(sqrt(Sxx),eps)*max(sqrt(Srr),eps))  (rows along D)
//   b = -(1/(D*B)) * sum_cols Sxr/(max(sqrt(Sxx),eps)*max(sqrt(Srr),eps))  (cols along N)
// R4: row loop unrolled x4 -> 16 loads in flight per wave, 12 butterfly chains
// batched (chain latency amortized 4x). Col-exchange epilogue as in R3.

#define BB 32
#define NN 4096
#define DD 512

static constexpr float EPS = 1e-12f;
static constexpr int BPB   = 64;          // blocks per batch
static constexpr int RPB   = NN / BPB;    // 64 rows per block
static constexpr int NWAVE = 4;           // 256 threads
static constexpr int RPW   = RPB / NWAVE; // 16 rows per wave
static constexpr int SUB   = 4;           // rows per super-iteration
static constexpr int NSUB  = RPW / SUB;   // 4

// ws layout (floats): cxx[B*D] | crr[B*D] | cxr[B*D] | row_tot[1]
static constexpr size_t WS_CXX = 0;
static constexpr size_t WS_CRR = (size_t)BB * DD;
static constexpr size_t WS_CXR = (size_t)2 * BB * DD;
static constexpr size_t WS_ROW = (size_t)3 * BB * DD;
static constexpr size_t WS_FLOATS = WS_ROW + 1;

__global__ __launch_bounds__(256, 4) void spl_pass1(
    const float* __restrict__ x, const float* __restrict__ r, float* __restrict__ ws) {
  // col exchange buffer, half-D at a time: [wave][m][256] floats = 12 KiB
  __shared__ float lds[NWAVE][3][DD / 2];
  __shared__ float ldsrow[NWAVE];

  const int tid  = threadIdx.x;
  const int wave = tid >> 6;
  const int lane = tid & 63;
  const int blk  = blockIdx.x;
  const int b    = blk / BPB;
  const int bib  = blk % BPB;
  const int n0   = bib * RPB + wave * RPW;

  float cxx[8], crr[8], cxr[8];
#pragma unroll
  for (int j = 0; j < 8; ++j) { cxx[j] = 0.f; crr[j] = 0.f; cxr[j] = 0.f; }
  float rowacc = 0.f;

  const size_t base = (size_t)b * NN * DD + (size_t)n0 * DD;
  const float* xb = x + base;
  const float* rb = r + base;

#pragma unroll 1
  for (int s = 0; s < NSUB; ++s) {
    // ---- phase 1: issue all 16 loads for 4 rows (16 KiB/wave in flight)
    float4 xd[SUB][2], rd[SUB][2];
#pragma unroll
    for (int rr = 0; rr < SUB; ++rr) {
      const float4* xp = (const float4*)(xb + (size_t)(s * SUB + rr) * DD);
      const float4* rp = (const float4*)(rb + (size_t)(s * SUB + rr) * DD);
      xd[rr][0] = xp[lane];
      xd[rr][1] = xp[lane + 64];
      rd[rr][0] = rp[lane];
      rd[rr][1] = rp[lane + 64];
    }

    // ---- phase 2: FMAs (row partials + column accumulators)
    float sxx[SUB], srr[SUB], sxr[SUB];
#pragma unroll
    for (int rr = 0; rr < SUB; ++rr) {
      sxx[rr] = 0.f; srr[rr] = 0.f; sxr[rr] = 0.f;
#pragma unroll
      for (int k = 0; k < 2; ++k) {
        const float xs[4] = {xd[rr][k].x, xd[rr][k].y, xd[rr][k].z, xd[rr][k].w};
        const float rs[4] = {rd[rr][k].x, rd[rr][k].y, rd[rr][k].z, rd[rr][k].w};
#pragma unroll
        for (int j = 0; j < 4; ++j) {
          const float pxx = xs[j] * xs[j];
          const float prr = rs[j] * rs[j];
          const float pxr = xs[j] * rs[j];
          sxx[rr] += pxx; srr[rr] += prr; sxr[rr] += pxr;
          cxx[k * 4 + j] += pxx; crr[k * 4 + j] += prr; cxr[k * 4 + j] += pxr;
        }
      }
    }

    // ---- phase 3: 12 independent butterfly chains, interleaved
#pragma unroll
    for (int off = 1; off < 64; off <<= 1) {
#pragma unroll
      for (int rr = 0; rr < SUB; ++rr) {
        sxx[rr] += __shfl_xor(sxx[rr], off, 64);
        srr[rr] += __shfl_xor(srr[rr], off, 64);
        sxr[rr] += __shfl_xor(sxr[rr], off, 64);
      }
    }
#pragma unroll
    for (int rr = 0; rr < SUB; ++rr) {
      const float nx = fmaxf(sqrtf(sxx[rr]), EPS);
      const float nr = fmaxf(sqrtf(srr[rr]), EPS);
      rowacc += sxr[rr] / (nx * nr);
    }
  }

  if (lane == 0) ldsrow[wave] = rowacc;

  // ---- column exchange, half 0: d in [0,256), reg slots 0..3
  __syncthreads();
  {
    float4* cb = (float4*)&lds[0][0][0];  // [wave*3+m][64] float4s
#pragma unroll
    for (int m = 0; m < 3; ++m) {
      const float* c = (m == 0) ? cxx : (m == 1) ? crr : cxr;
      cb[(wave * 3 + m) * 64 + lane] = make_float4(c[0], c[1], c[2], c[3]);
    }
  }
  __syncthreads();
  for (int i = tid; i < 768; i += 256) {
    const int m = i >> 8;
    const int d = i & 255;
    const float sum = lds[0][m][d] + lds[1][m][d] + lds[2][m][d] + lds[3][m][d];
    atomicAdd(ws + (size_t)m * BB * DD + (size_t)b * DD + d, sum);
  }

  // ---- column exchange, half 1: d in [256,512), reg slots 4..7
  __syncthreads();
  {
    float4* cb = (float4*)&lds[0][0][0];
#pragma unroll
    for (int m = 0; m < 3; ++m) {
      const float* c = (m == 0) ? cxx : (m == 1) ? crr : cxr;
      cb[(wave * 3 + m) * 64 + lane] = make_float4(c[4], c[5], c[6], c[7]);
    }
  }
  __syncthreads();
  for (int i = tid; i < 768; i += 256) {
    const int m = i >> 8;
    const int d = i & 255;
    const float sum = lds[0][m][d] + lds[1][m][d] + lds[2][m][d] + lds[3][m][d];
    atomicAdd(ws + (size_t)m * BB * DD + (size_t)b * DD + 256 + d, sum);
  }

  if (tid == 0) {
    atomicAdd(ws + WS_ROW, ldsrow[0] + ldsrow[1] + ldsrow[2] + ldsrow[3]);
  }
}

__global__ __launch_bounds__(256) void spl_pass2(const float* __restrict__ ws,
                                                 float* __restrict__ out) {
  const int tid = threadIdx.x;
  const float* cxx_g = ws + WS_CXX;
  const float* crr_g = ws + WS_CRR;
  const float* cxr_g = ws + WS_CXR;

  float acc = 0.f;
  for (int i = tid; i < BB * DD; i += 256) {
    const float sxx = cxx_g[i];
    const float srr = crr_g[i];
    const float sxr = cxr_g[i];
    const float nx = fmaxf(sqrtf(sxx), EPS);
    const float nr = fmaxf(sqrtf(srr), EPS);
    acc += sxr / (nx * nr);
  }
#pragma unroll
  for (int off = 1; off < 64; off <<= 1) acc += __shfl_xor(acc, off, 64);

  __shared__ float wsum[4];
  if ((tid & 63) == 0) wsum[tid >> 6] = acc;
  __syncthreads();
  if (tid == 0) {
    const float colsum = wsum[0] + wsum[1] + wsum[2] + wsum[3];
    const float rowsum = ws[WS_ROW];
    const float a = -rowsum / ((float)NN * (float)BB);
    const float b = -colsum / ((float)DD * (float)BB);
    out[0] = a + b;
  }
}

extern "C" void kernel_launch(void* const* d_in, const int* in_sizes, int n_in,
                              void* d_out, int out_size, void* d_ws, size_t ws_size,
                              hipStream_t stream) {
  const float* x = (const float*)d_in[0];
  const float* r = (const float*)d_in[1];
  float* out = (float*)d_out;
  float* ws = (float*)d_ws;

  (void)in_sizes; (void)n_in; (void)out_size; (void)ws_size;

  hipMemsetAsync(ws, 0, WS_FLOATS * sizeof(float), stream);
  spl_pass1<<<BB * BPB, 256, 0, stream>>>(x, r, ws);
  spl_pass2<<<1, 256, 0, stream>>>(ws, out);
}